// Round 6
// baseline (412.860 us; speedup 1.0000x reference)
//
#include <hip/hip_runtime.h>

#define D_IN   256
#define HID    256
#define NNODES 100000
#define NEDGE  262144

typedef short short8            __attribute__((ext_vector_type(8)));
typedef float float4v           __attribute__((ext_vector_type(4)));
typedef unsigned short ushort8  __attribute__((ext_vector_type(8)));

__device__ __forceinline__ unsigned short f32_to_bf16_rne(float f) {
    unsigned int u = __float_as_uint(f);
    unsigned int r = u + 0x7FFFu + ((u >> 16) & 1u);
    return (unsigned short)(r >> 16);
}
// round-half-up: 1 ulp-tie difference vs RNE, half the VALU cost (hot path)
__device__ __forceinline__ unsigned short f32_to_bf16_rnu(float f) {
    return (unsigned short)((__float_as_uint(f) + 0x8000u) >> 16);
}
__device__ __forceinline__ float bf16_to_f32(unsigned short h) {
    return __uint_as_float(((unsigned int)h) << 16);
}

// -------- W1 (fp32 [2*256][256], k-major) -> Wt (bf16 [z][n][k]) — LDS tile transpose --------
__global__ __launch_bounds__(256) void convert_w(
    const float* __restrict__ W1, unsigned short* __restrict__ Wt)
{
    __shared__ float tile[64][65];
    const int z = blockIdx.z, kb = blockIdx.x * 64, nb = blockIdx.y * 64;
    const int t = threadIdx.x;
    const int g = t >> 6, c = t & 63;
#pragma unroll
    for (int r = 0; r < 16; r++) {
        int kl = g * 16 + r;
        tile[kl][c] = W1[((size_t)(z * 256 + kb + kl)) * 256 + nb + c];
    }
    __syncthreads();
#pragma unroll
    for (int r = 0; r < 16; r++) {
        int nl = g * 16 + r;
        Wt[((size_t)(z * 256 + nb + nl)) * 256 + kb + c] = f32_to_bf16_rne(tile[c][nl]);
    }
}

// -------- Phase 1: U = Xsrc@W1_top + b1 (bf16), V = Xdst@W1_bot (bf16) --------
// BARRIER-FREE K-LOOP (rounds 2-5 showed the 2-barrier K-loop is the structural
// limit: occupancy 20->42% made it SLOWER). Whole B slice (256x256 bf16) lives
// in LDS, loaded once (132 KB, stride 264 = 33 superbanks -> conflict-free).
// A fragments load DIRECTLY global->regs (A-frag is 8 k-contiguous fp32/lane =
// two float4), packed to bf16 in-register. K-loop = pure dataflow, no syncs.
// Block: 128 rows x 256 N, 512 thr = 8 waves (2m x 4n), wave tile 64x64
// (acc[4][4] = 64 AGPR). 1 block/CU (LDS-capped) -> VGPRs are free: (512,2).
#define BSTR 264   // B k-stride in ushorts: 528 B = 33 x 16B superbanks (odd -> even spread)

__global__ __launch_bounds__(512, 2) void gemm_xw_mfma(
    const float* __restrict__ Xsrc, const float* __restrict__ Xdst,
    const unsigned short* __restrict__ Wt, const float* __restrict__ b1,
    unsigned short* __restrict__ U, unsigned short* __restrict__ V)
{
    const int zz = blockIdx.z;
    const float* X = zz ? Xdst : Xsrc;
    const unsigned short* Wz = Wt + (size_t)zz * 256 * 256;
    unsigned short* C = zz ? V : U;

    const int m0 = blockIdx.x * 128;

    __shared__ __align__(16) unsigned short smem[256 * BSTR];   // 132 KB
    unsigned short* Bs = smem;

    const int t = threadIdx.x;
    const int w = t >> 6, lane = t & 63;
    const int wm = w >> 2, wn = w & 3;          // 2m x 4n wave grid
    const int quad = lane >> 4, l16 = lane & 15;

    // ---- load full B slice into LDS (once) ----
#pragma unroll
    for (int i = 0; i < 16; i++) {
        int c = t + i * 512;                    // 0..8191 chunks of 16 B
        int n = c >> 5, s = (c & 31) << 3;
        *(int4*)(Bs + n * BSTR + s) = *(const int4*)(Wz + (size_t)n * 256 + s);
    }

    // hoisted, clamped A row pointers (loop-invariant)
    const float* arow[4];
#pragma unroll
    for (int mi = 0; mi < 4; mi++) {
        int gr = m0 + wm * 64 + mi * 16 + l16;
        if (gr >= NNODES) gr = NNODES - 1;
        arow[mi] = X + (size_t)gr * D_IN + quad * 8;
    }

    float4v acc[4][4];
#pragma unroll
    for (int mi = 0; mi < 4; mi++)
#pragma unroll
        for (int ni = 0; ni < 4; ni++) acc[mi][ni] = (float4v){0.f, 0.f, 0.f, 0.f};

    __syncthreads();                            // B ready — the ONLY K-path barrier

    // ---- K-loop: no barriers, compiler free to pipeline across steps ----
#pragma unroll
    for (int ks = 0; ks < D_IN; ks += 32) {
        short8 af[4], bf[4];
#pragma unroll
        for (int mi = 0; mi < 4; mi++) {
            float4 a0 = *(const float4*)(arow[mi] + ks);
            float4 a1 = *(const float4*)(arow[mi] + ks + 4);
            short8 v;
            v[0] = (short)f32_to_bf16_rnu(a0.x); v[1] = (short)f32_to_bf16_rnu(a0.y);
            v[2] = (short)f32_to_bf16_rnu(a0.z); v[3] = (short)f32_to_bf16_rnu(a0.w);
            v[4] = (short)f32_to_bf16_rnu(a1.x); v[5] = (short)f32_to_bf16_rnu(a1.y);
            v[6] = (short)f32_to_bf16_rnu(a1.z); v[7] = (short)f32_to_bf16_rnu(a1.w);
            af[mi] = v;
        }
#pragma unroll
        for (int ni = 0; ni < 4; ni++)
            bf[ni] = *(const short8*)(Bs + (wn * 64 + ni * 16 + l16) * BSTR + ks + quad * 8);
#pragma unroll
        for (int mi = 0; mi < 4; mi++)
#pragma unroll
            for (int ni = 0; ni < 4; ni++)
                acc[mi][ni] = __builtin_amdgcn_mfma_f32_16x16x32_bf16(
                    af[mi], bf[ni], acc[mi][ni], 0, 0, 0);
    }

    // ---- epilogue: bias fold (z==0), bf16 pack, LDS-staged coalesced store ----
    float bias[4];
#pragma unroll
    for (int ni = 0; ni < 4; ni++)
        bias[ni] = (zz == 0) ? b1[wn * 64 + ni * 16 + l16] : 0.f;

    __syncthreads();                            // all waves done reading Bs
    unsigned short* Cs = smem;                  // [128][136] = 34.8 KB, aliases Bs
#pragma unroll
    for (int h = 0; h < 2; h++) {               // n-halves 0..127, 128..255
        if ((wn >> 1) == h) {
#pragma unroll
            for (int mi = 0; mi < 4; mi++)
#pragma unroll
                for (int ni = 0; ni < 4; ni++) {
                    int cl = (wn & 1) * 64 + ni * 16 + l16;
#pragma unroll
                    for (int r = 0; r < 4; r++) {
                        int row = wm * 64 + mi * 16 + quad * 4 + r;
                        Cs[row * 136 + cl] = f32_to_bf16_rne(acc[mi][ni][r] + bias[ni]);
                    }
                }
        }
        __syncthreads();
        // 128 rows x 128 cols = 2048 int4 chunks / 512 thr = 4 each
#pragma unroll
        for (int i = 0; i < 4; i++) {
            int s = t + i * 512;
            int row = s >> 4, seg = s & 15;
            int gr = m0 + row;
            if (gr < NNODES)
                *(int4*)(C + (size_t)gr * HID + h * 128 + seg * 8) =
                    *(const int4*)(Cs + row * 136 + seg * 8);
        }
        __syncthreads();
    }
}

// -------- Phase 2: out[e] = relu(U[s]+V[d]) . W2 + b2   (b1 folded into U) --------
// 16 edges per wave, half-wave pairing; one 1 KB wave-load per row gather.
__global__ __launch_bounds__(256) void edge_score_bf16(
    const unsigned short* __restrict__ U, const unsigned short* __restrict__ V,
    const float* __restrict__ W2, const float* __restrict__ b2,
    const int* __restrict__ epos, const int* __restrict__ eneg,
    float* __restrict__ out)
{
    const int w = threadIdx.x >> 6, lane = threadIdx.x & 63;
    const int half = lane >> 5, hl = lane & 31;
    const int ebase = blockIdx.x * 64 + w * 16;

    const int* ei = (ebase < NEDGE) ? epos : eneg;
    const int eb2 = (ebase < NEDGE) ? ebase : ebase - NEDGE;

    int sidx[8], didx[8];
#pragma unroll
    for (int p = 0; p < 8; p++) {
        int e = eb2 + 2 * p + half;
        sidx[p] = ei[e];
        didx[p] = ei[NEDGE + e];
    }
    ushort8 uu[8], vv[8];
#pragma unroll
    for (int p = 0; p < 8; p++)
        uu[p] = *(const ushort8*)(U + (size_t)sidx[p] * HID + hl * 8);
#pragma unroll
    for (int p = 0; p < 8; p++)
        vv[p] = *(const ushort8*)(V + (size_t)didx[p] * HID + hl * 8);

    float w2r[8];
    *(float4*)&w2r[0] = *(const float4*)(W2 + hl * 8);
    *(float4*)&w2r[4] = *(const float4*)(W2 + hl * 8 + 4);
    const float bb2 = b2[0];

#pragma unroll
    for (int p = 0; p < 8; p++) {
        float s = 0.f;
#pragma unroll
        for (int q = 0; q < 8; q++)
            s += fmaxf(bf16_to_f32(uu[p][q]) + bf16_to_f32(vv[p][q]), 0.f) * w2r[q];
#pragma unroll
        for (int off = 16; off; off >>= 1)
            s += __shfl_xor(s, off, 64);
        if (hl == 0) out[ebase + 2 * p + half] = s + bb2;
    }
}

// -------- Fallback (ws too small): direct per-edge MLP --------
__global__ __launch_bounds__(256) void edge_score_direct(
    const float* __restrict__ xs_, const float* __restrict__ xd_,
    const float* __restrict__ W1, const float* __restrict__ b1,
    const float* __restrict__ W2, const float* __restrict__ b2,
    const int* __restrict__ epos, const int* __restrict__ eneg,
    float* __restrict__ out)
{
    __shared__ float xrow[2 * D_IN];
    __shared__ float red[256];
    const int e = blockIdx.x;
    const int* ei = (e < NEDGE) ? epos : eneg;
    const int e2  = (e < NEDGE) ? e : e - NEDGE;
    const int s = ei[e2];
    const int d = ei[NEDGE + e2];
    const int t = threadIdx.x;

    xrow[t]        = xs_[(size_t)s * D_IN + t];
    xrow[D_IN + t] = xd_[(size_t)d * D_IN + t];
    __syncthreads();

    float acc = b1[t];
    for (int k = 0; k < 2 * D_IN; k++)
        acc += xrow[k] * W1[(size_t)k * HID + t];
    acc = fmaxf(acc, 0.f);
    red[t] = acc * W2[t];
    __syncthreads();
    for (int st = 128; st; st >>= 1) {
        if (t < st) red[t] += red[t + st];
        __syncthreads();
    }
    if (t == 0) out[e] = red[0] + b2[0];
}

extern "C" void kernel_launch(void* const* d_in, const int* in_sizes, int n_in,
                              void* d_out, int out_size, void* d_ws, size_t ws_size,
                              hipStream_t stream) {
    const float* x_src = (const float*)d_in[0];
    const float* x_dst = (const float*)d_in[1];
    const float* W1    = (const float*)d_in[2];
    const float* b1    = (const float*)d_in[3];
    const float* W2    = (const float*)d_in[4];
    const float* b2    = (const float*)d_in[5];
    const int*   epos  = (const int*)d_in[6];
    const int*   eneg  = (const int*)d_in[7];
    float* out = (float*)d_out;

    const size_t uv   = (size_t)NNODES * HID;
    const size_t need = (2 * uv + 2 * 256 * 256) * sizeof(unsigned short);
    if (ws_size >= need) {
        unsigned short* U  = (unsigned short*)d_ws;
        unsigned short* V  = U + uv;
        unsigned short* Wt = V + uv;
        convert_w<<<dim3(4, 4, 2), 256, 0, stream>>>(W1, Wt);
        dim3 g1((NNODES + 127) / 128, 1, 2);
        gemm_xw_mfma<<<g1, 512, 0, stream>>>(x_src, x_dst, Wt, b1, U, V);
        edge_score_bf16<<<(2 * NEDGE) / 64, 256, 0, stream>>>(U, V, W2, b2, epos, eneg, out);
    } else {
        edge_score_direct<<<2 * NEDGE, 256, 0, stream>>>(x_src, x_dst, W1, b1, W2, b2, epos, eneg, out);
    }
}